// Round 19
// baseline (21.421 us; speedup 1.0000x reference)
//
#include <hip/hip_runtime.h>
#include <math.h>

#define N  2048
#define K  8
#define NK 1024
#define R  4             // rows per block
#define TPB 512
#define SLOT NK          // zero slot index in stage rows
#define TAU_C 0.5f
#define TAU_S 0.5f

// Single fused kernel (replay-safe class, R8-R18). R18 math (19.6us) + T14
// async-STAGE split with an LDS double buffer:
//   per row: issue next row's global loads -> PASS(current) -> drain+ds_write
//   -> ONE barrier. HBM latency (~900cy, adj is L3-cold read-once) hides under
//   the ~600cy PASS instead of stalling all 16 waves in lockstep.
// Buffer B aliases the jj map (dead after the jc hoist) -> LDS stays ~67KB,
// 2 blocks/CU.

// PASS A+B for one row, reading stage buffer CUR. R18-proven math:
//  sum/sumsq/cs accumulation (select-free via zero slot), identity-vs,
//  rcp-LUT mean, bounds-LUT decision, byte-exact in-band fallback.
#define ROW_PASS(rr, CUR)                                                      \
    {                                                                          \
        int kpC = 0;                                                           \
        _Pragma("unroll")                                                      \
        for (int k = 0; k < K; ++k) {                                          \
            int v_ = (int)ixs[k][rr];                                          \
            kpC |= (__builtin_amdgcn_readfirstlane(v_) >= 0) ? (1 << k) : 0;   \
        }                                                                      \
        float sum[4]   = {0.f, 0.f, 0.f, 0.f};                                 \
        float sumsq[4] = {0.f, 0.f, 0.f, 0.f};                                 \
        int   csi[4]   = {0, 0, 0, 0};                                         \
        _Pragma("unroll")                                                      \
        for (int k = 0; k < K; ++k) {                                          \
            if ((kpC >> k) & 1) {                    /* SGPR branch */         \
                _Pragma("unroll")                                              \
                for (int yy = 0; yy < 4; ++yy) {                               \
                    float a = CUR[k][jc[k][yy]];     /* ds_read_b32 */         \
                    sum[yy]   += a;                  /* +0.0 absent == ref */  \
                    sumsq[yy]  = fmaf(a, a, sumsq[yy]);                        \
                    csi[yy]   += (a > TAU_C) ? 1 : 0;                          \
                }                                                              \
            }                                                                  \
        }                                                                      \
        float res[4];                                                          \
        _Pragma("unroll")                                                      \
        for (int yy = 0; yy < 4; ++yy) {                                       \
            const int m   = jmask[yy] & kpC;                                   \
            const int cnt = __popc(m);                                         \
            const float cf = (float)cnt;                                       \
            float mean = sum[yy] * lutR[cnt];        /* exact cnt=1,2,4,8 */   \
            float t    = fmaf(cf, mean, -2.0f * sum[yy]);                      \
            float vsf  = fmaf(mean, t, sumsq[yy]);   /* ~vs, err <~1e-5 */     \
            const int li = cnt * 9 + csi[yy];                                  \
            float2 bb = lutB[li];                                              \
            float rr_;                                                         \
            if (__builtin_expect(vsf >= bb.x && vsf <= bb.y, 0)) {             \
                float n      = fmaxf(cf, 1e-5f);                               \
                float mean_e = sum[yy] / n;          /* IEEE divide */         \
                float vs = 0.f;                                                \
                _Pragma("unroll")                                              \
                for (int k = 0; k < K; ++k) {                                  \
                    if ((kpC >> k) & 1) {                                      \
                        bool  p = (m >> k) & 1;                                \
                        float a = CUR[k][jc[k][yy]];                           \
                        float d = a - mean_e;                                  \
                        vs += p ? d * d : 0.f;       /* select blocks fma */   \
                    }                                                          \
                }                                                              \
                float C = lutCS[li];                 /* == cs/n, ref bits */   \
                float V = vs / n;                    /* IEEE divide */         \
                float S = C * expf(-V);              /* precise expf */        \
                rr_ = (S > TAU_S && cnt > 0) ? mean_e : 0.f;                   \
            } else {                                                           \
                rr_ = (vsf < bb.x) ? mean : 0.f;     /* certain acc/rej */     \
            }                                                                  \
            res[yy] = rr_;                                                     \
        }                                                                      \
        float4 o_;                                                             \
        o_.x = res[0]; o_.y = res[1]; o_.z = res[2]; o_.w = res[3];            \
        *(float4*)(out + (size_t)(X0 + (rr)) * N + y0) = o_;                   \
    }

// Full pipelined row: issue loads for row rr+1, PASS on rr from CUR,
// then drain + write into NXT + one barrier. sched_barrier(0) pins the
// loads above the PASS and the writes below it (defeats the re-fuse).
#define ROW_STEP(rr, CUR, NXT)                                                 \
    {                                                                          \
        int kpN = 0, ixN_[K];                                                  \
        _Pragma("unroll")                                                      \
        for (int k = 0; k < K; ++k) {                                          \
            int v_ = (int)ixs[k][(rr) + 1];                                    \
            ixN_[k] = __builtin_amdgcn_readfirstlane(v_);                      \
            kpN |= (ixN_[k] >= 0) ? (1 << k) : 0;                              \
        }                                                                      \
        float2 sr[K];                                                          \
        _Pragma("unroll")                                                      \
        for (int k = 0; k < K; ++k) {                                          \
            if ((kpN >> k) & 1) {                    /* SGPR branch */         \
                const float2* __restrict__ src_ =                              \
                    (const float2*)(adj + ((size_t)k * NK +                    \
                                           (size_t)ixN_[k]) * NK);             \
                sr[k] = src_[tid];                   /* coalesced 8B */        \
            }                                                                  \
        }                                                                      \
        __builtin_amdgcn_sched_barrier(0);           /* loads stay above */    \
        ROW_PASS(rr, CUR)                                                      \
        __builtin_amdgcn_sched_barrier(0);           /* writes stay below */   \
        _Pragma("unroll")                                                      \
        for (int k = 0; k < K; ++k) {                                          \
            if ((kpN >> k) & 1)                                                \
                ((float2*)&NXT[k][0])[tid] = sr[k];  /* vmcnt auto-wait */     \
        }                                                                      \
        __syncthreads();                             /* NXT visible */         \
    }

__global__ void __launch_bounds__(TPB, 4)
fia_fused(const float* __restrict__ adj,
          const int*   __restrict__ idx,
          float* __restrict__ out) {
    __shared__ float stA[K][NK + 4];     // 32.9 KB stage buffer A
    __shared__ union {
        short jj[K][N];                  // 32 KB, dead after jc hoist
        float stB[K][NK + 4];            // 32.9 KB stage buffer B
    } u;
    __shared__ short  ixs[K][R];         // pos of row x in idx[k], or -1
    __shared__ float  lutCS[81];         // exact IEEE cs/n (ref C bits)
    __shared__ float2 lutB[81];          // (BloN, BhiN) decision bounds
    __shared__ float  lutR[16];          // 1/max(cnt,1e-5)

    const int tid = threadIdx.x;
    const int X0  = blockIdx.x * R;

    // ---- one-time init: jj=-1, ixs=-1, stA zero slot, LUTs
    {
        int4  m1 = make_int4(-1, -1, -1, -1);
        int4* p4 = (int4*)&u.jj[0][0];               // 2048 int4
        #pragma unroll
        for (int q = 0; q < (K * N * 2) / (16 * TPB); ++q)   // 4
            p4[q * TPB + tid] = m1;
        if (tid < K * R) ((short*)ixs)[tid] = (short)-1;
        if (tid < K) stA[tid][SLOT] = 0.0f;
        if (tid < 16) lutR[tid] = 1.0f / fmaxf((float)tid, 1e-5f);
        if (tid < 81) {
            int cn = tid / 9, cc = tid % 9;
            float nn = fmaxf((float)cn, 1e-5f);
            float C  = (float)cc / nn;               // IEEE divide == ref bits
            lutCS[tid] = C;
            float lo, hi;
            if (2 * cc <= cn) { lo = -2.0f; hi = -1.0f; }    // always reject
            else {
                float B = logf(2.0f * C);            // V boundary: S = 0.5
                float d = 1e-3f * (1.0f + fabsf(B)); // >=100x all err sources
                lo = (B - d) * (float)cn;
                hi = (B + d) * (float)cn;
            }
            lutB[tid] = make_float2(lo, hi);
        }
    }
    __syncthreads();

    // ---- scan idx: int4 loads (R16-proven). Unique writer per cell.
    #pragma unroll
    for (int it = 0; it < (K * NK) / (4 * TPB); ++it) {      // 4
        int  t4   = it * TPB + tid;
        int4 w    = ((const int4*)idx)[t4];          // coalesced 16B
        int  base = t4 * 4;
        int  k    = base >> 10;
        int  p    = base & (NK - 1);
        u.jj[k][w.x] = (short)(p);
        u.jj[k][w.y] = (short)(p + 1);
        u.jj[k][w.z] = (short)(p + 2);
        u.jj[k][w.w] = (short)(p + 3);
        int r0 = w.x - X0, r1 = w.y - X0, r2 = w.z - X0, r3 = w.w - X0;
        if ((unsigned)r0 < (unsigned)R) ixs[k][r0] = (short)(p);
        if ((unsigned)r1 < (unsigned)R) ixs[k][r1] = (short)(p + 1);
        if ((unsigned)r2 < (unsigned)R) ixs[k][r2] = (short)(p + 2);
        if ((unsigned)r3 < (unsigned)R) ixs[k][r3] = (short)(p + 3);
    }
    __syncthreads();

    // ---- hoist per-thread column state from jj (LAST use of jj)
    const int y0 = tid * 4;                          // 4 consecutive columns
    int jc[K][4];                                    // gather index or SLOT
    int jmask[4] = {0, 0, 0, 0};
    #pragma unroll
    for (int k = 0; k < K; ++k) {
        short4 v = *(const short4*)&u.jj[k][y0];     // ds_read_b64
        int j0 = v.x, j1 = v.y, j2 = v.z, j3 = v.w;
        jmask[0] |= (j0 >= 0) ? (1 << k) : 0;
        jmask[1] |= (j1 >= 0) ? (1 << k) : 0;
        jmask[2] |= (j2 >= 0) ? (1 << k) : 0;
        jmask[3] |= (j3 >= 0) ? (1 << k) : 0;
        jc[k][0] = (j0 >= 0) ? j0 : SLOT;            // absent -> zero slot
        jc[k][1] = (j1 >= 0) ? j1 : SLOT;
        jc[k][2] = (j2 >= 0) ? j2 : SLOT;
        jc[k][3] = (j3 >= 0) ? j3 : SLOT;
    }
    __syncthreads();                                 // jj dead; stB writable

    // ---- stB zero slot + prologue: stage row 0 into stA
    if (tid < K) u.stB[tid][SLOT] = 0.0f;
    {
        int kp0 = 0, ix0[K];
        #pragma unroll
        for (int k = 0; k < K; ++k) {
            int v = (int)ixs[k][0];
            ix0[k] = __builtin_amdgcn_readfirstlane(v);
            kp0 |= (ix0[k] >= 0) ? (1 << k) : 0;
        }
        float2 s0[K];
        #pragma unroll
        for (int k = 0; k < K; ++k) {
            if ((kp0 >> k) & 1) {
                const float2* __restrict__ src =
                    (const float2*)(adj + ((size_t)k * NK + (size_t)ix0[k]) * NK);
                s0[k] = src[tid];                    // coalesced 8B
            }
        }
        #pragma unroll
        for (int k = 0; k < K; ++k) {
            if ((kp0 >> k) & 1)
                ((float2*)&stA[k][0])[tid] = s0[k];  // vmcnt auto-wait
        }
        __syncthreads();                             // stA + zero slots visible
    }

    // ---- pipelined rows (static buffer names, rule #20)
    ROW_STEP(0, stA,   u.stB)
    ROW_STEP(1, u.stB, stA)
    ROW_STEP(2, stA,   u.stB)
    ROW_PASS(3, u.stB)                               // last row: no prefetch
}

extern "C" void kernel_launch(void* const* d_in, const int* in_sizes, int n_in,
                              void* d_out, int out_size, void* d_ws, size_t ws_size,
                              hipStream_t stream) {
    const float* adj = (const float*)d_in[0];        // (K, NK, NK) f32
    const int*   idx = (const int*)d_in[1];          // (K, NK) i32
    float*       out = (float*)d_out;                // (N, N) f32

    dim3 block(TPB, 1, 1);
    dim3 grid(N / R, 1, 1);                          // 512 blocks x 4 rows
    fia_fused<<<grid, block, 0, stream>>>(adj, idx, out);
}